// Round 5
// baseline (243.466 us; speedup 1.0000x reference)
//
#include <hip/hip_runtime.h>
#include <hip/hip_bf16.h>

#define NUM_BUCKETS 8192
#define ROW_THREADS 256

typedef float f32x4 __attribute__((ext_vector_type(4)));

// Kernel 1: exclusive prefix sum of row_lengths -> offs[0..B].
// Single block, 1024 threads, 16 elems/thread, shfl-based (~4 barriers/chunk).
__global__ __launch_bounds__(1024) void scan_rows_kernel(
    const int* __restrict__ row_len, int* __restrict__ offs, int B) {
    __shared__ int wave_sums[16];
    __shared__ int carry_s;
    const int t = threadIdx.x;
    const int wave = t >> 6, lane = t & 63;
    if (t == 0) carry_s = 0;
    __syncthreads();
    const int CHUNK = 1024 * 16;
    for (int base = 0; base < B; base += CHUNK) {
        int v[16];
        const int idx0 = base + t * 16;
        int local = 0;
        #pragma unroll
        for (int e = 0; e < 16; ++e) {
            const int i = idx0 + e;
            const int x = (i < B) ? row_len[i] : 0;
            v[e] = local;          // exclusive within thread
            local += x;
        }
        int incl = local;
        #pragma unroll
        for (int d = 1; d < 64; d <<= 1) {
            const int y = __shfl_up(incl, d, 64);
            if (lane >= d) incl += y;
        }
        if (lane == 63) wave_sums[wave] = incl;
        __syncthreads();
        if (wave == 0) {
            int s = (lane < 16) ? wave_sums[lane] : 0;
            #pragma unroll
            for (int d = 1; d < 16; d <<= 1) {
                const int y = __shfl_up(s, d, 64);
                if (lane >= d) s += y;
            }
            if (lane < 16) wave_sums[lane] = s;
        }
        __syncthreads();
        const int carry = carry_s;
        const int wave_excl = (wave == 0) ? 0 : wave_sums[wave - 1];
        const int texcl = carry + wave_excl + (incl - local);
        #pragma unroll
        for (int e = 0; e < 16; ++e) {
            const int i = idx0 + e;
            if (i < B) offs[i] = texcl + v[e];
        }
        if (t == 0 && base + CHUNK >= B) offs[B] = carry + wave_sums[15];
        __syncthreads();
        if (t == 0) carry_s = carry + wave_sums[15];
        __syncthreads();
    }
}

// Kernel 2: one block per row, NO LDS. Zero the row directly in global with
// plain coalesced dwordx4 stores (full-line coverage -> no read-allocate,
// lines land dirty in L2). __syncthreads() drains vmcnt so the zeros are
// visible at L2, then <=50 global atomics hit the still-resident L2 lines.
// HBM traffic = one eviction per line = exactly 512 MiB, fully decoupled
// from block execution (same mechanism as __amd_rocclr_fillBufferAligned).
__global__ __launch_bounds__(ROW_THREADS) void nhot_direct_kernel(
    const int* __restrict__ ids, const float* __restrict__ w,
    const int* __restrict__ offs, float* __restrict__ out) {
    const int r = blockIdx.x;
    const int t = threadIdx.x;

    float* rowp = out + (size_t)r * NUM_BUCKETS;
    f32x4* outv = reinterpret_cast<f32x4*>(rowp);
    const f32x4 z = {0.f, 0.f, 0.f, 0.f};

    // fetch payload before the store-drain barrier so the loads overlap it
    const int s = offs[r];
    const int e = offs[r + 1];
    const int n = e - s;
    int id = 0; float wt = 0.f;
    if (t < n) { id = ids[s + t]; wt = w[s + t]; }

    #pragma unroll
    for (int k = 0; k < NUM_BUCKETS / 4 / ROW_THREADS; ++k)  // 8 x 1KB/wave
        outv[k * ROW_THREADS + t] = z;

    __syncthreads();  // vmcnt(0): zeros are in L2, visible to atomics

    if (t < n) atomicAdd(&rowp[id], wt);
    for (int i = s + t + ROW_THREADS; i < e; i += ROW_THREADS)  // general tail
        atomicAdd(&rowp[ids[i]], w[i]);
}

extern "C" void kernel_launch(void* const* d_in, const int* in_sizes, int n_in,
                              void* d_out, int out_size, void* d_ws, size_t ws_size,
                              hipStream_t stream) {
    const int*   ids     = (const int*)d_in[0];    // values (NNZ,1) int32
    const int*   row_len = (const int*)d_in[1];    // row_lengths (B,1) int32
    const float* wvals   = (const float*)d_in[2];  // weight_values (NNZ,1) f32
    // d_in[3] = weight_row_lengths (unused by reference)

    const int B = in_sizes[1];
    float* out = (float*)d_out;
    int* offs = (int*)d_ws;  // needs (B+1)*4 bytes

    scan_rows_kernel<<<1, 1024, 0, stream>>>(row_len, offs, B);
    nhot_direct_kernel<<<B, ROW_THREADS, 0, stream>>>(ids, wvals, offs, out);
}

// Round 6
// 118.041 us; speedup vs baseline: 2.0626x; 2.0626x over previous
//
#include <hip/hip_runtime.h>
#include <hip/hip_bf16.h>

#define NUM_BUCKETS 8192
#define ROW_THREADS 256

typedef float f32x4 __attribute__((ext_vector_type(4)));

// Kernel 1: exclusive prefix sum of row_lengths -> offs[0..B].
// Single block, 1024 threads, 16 elems/thread, shfl-based (~4 barriers/chunk).
__global__ __launch_bounds__(1024) void scan_rows_kernel(
    const int* __restrict__ row_len, int* __restrict__ offs, int B) {
    __shared__ int wave_sums[16];
    __shared__ int carry_s;
    const int t = threadIdx.x;
    const int wave = t >> 6, lane = t & 63;
    if (t == 0) carry_s = 0;
    __syncthreads();
    const int CHUNK = 1024 * 16;
    for (int base = 0; base < B; base += CHUNK) {
        int v[16];
        const int idx0 = base + t * 16;
        int local = 0;
        #pragma unroll
        for (int e = 0; e < 16; ++e) {
            const int i = idx0 + e;
            const int x = (i < B) ? row_len[i] : 0;
            v[e] = local;          // exclusive within thread
            local += x;
        }
        int incl = local;
        #pragma unroll
        for (int d = 1; d < 64; d <<= 1) {
            const int y = __shfl_up(incl, d, 64);
            if (lane >= d) incl += y;
        }
        if (lane == 63) wave_sums[wave] = incl;
        __syncthreads();
        if (wave == 0) {
            int s = (lane < 16) ? wave_sums[lane] : 0;
            #pragma unroll
            for (int d = 1; d < 16; d <<= 1) {
                const int y = __shfl_up(s, d, 64);
                if (lane >= d) s += y;
            }
            if (lane < 16) wave_sums[lane] = s;
        }
        __syncthreads();
        const int carry = carry_s;
        const int wave_excl = (wave == 0) ? 0 : wave_sums[wave - 1];
        const int texcl = carry + wave_excl + (incl - local);
        #pragma unroll
        for (int e = 0; e < 16; ++e) {
            const int i = idx0 + e;
            if (i < B) offs[i] = texcl + v[e];
        }
        if (t == 0 && base + CHUNK >= B) offs[B] = carry + wave_sums[15];
        __syncthreads();
        if (t == 0) carry_s = carry + wave_sums[15];
        __syncthreads();
    }
}

// Kernel 2: one block per row (R3 structure — best measured). Payload loads
// hoisted before the LDS zero so global latency hides under it; plain
// coalesced dwordx4 stores (A/B vs nontemporal).
__global__ __launch_bounds__(ROW_THREADS) void nhot_row_kernel(
    const int* __restrict__ ids, const float* __restrict__ w,
    const int* __restrict__ offs, float* __restrict__ out) {
    __shared__ float lds[NUM_BUCKETS];
    const int r = blockIdx.x;
    const int t = threadIdx.x;

    // issue payload loads first; they complete while we zero LDS
    const int s = offs[r];
    const int e = offs[r + 1];
    const int n = e - s;
    int id = 0; float wt = 0.f;
    if (t < n) { id = ids[s + t]; wt = w[s + t]; }

    f32x4* ldsv = reinterpret_cast<f32x4*>(lds);
    const f32x4 z = {0.f, 0.f, 0.f, 0.f};
    #pragma unroll
    for (int k = 0; k < NUM_BUCKETS / 4 / ROW_THREADS; ++k)  // 8 x ds_write_b128
        ldsv[k * ROW_THREADS + t] = z;
    __syncthreads();

    if (t < n) atomicAdd(&lds[id], wt);
    for (int i = s + t + ROW_THREADS; i < e; i += ROW_THREADS)  // general tail
        atomicAdd(&lds[ids[i]], w[i]);
    __syncthreads();

    f32x4* outv = reinterpret_cast<f32x4*>(out + (size_t)r * NUM_BUCKETS);
    #pragma unroll
    for (int k = 0; k < NUM_BUCKETS / 4 / ROW_THREADS; ++k)  // 8 x dwordx4
        outv[k * ROW_THREADS + t] = ldsv[k * ROW_THREADS + t];
}

extern "C" void kernel_launch(void* const* d_in, const int* in_sizes, int n_in,
                              void* d_out, int out_size, void* d_ws, size_t ws_size,
                              hipStream_t stream) {
    const int*   ids     = (const int*)d_in[0];    // values (NNZ,1) int32
    const int*   row_len = (const int*)d_in[1];    // row_lengths (B,1) int32
    const float* wvals   = (const float*)d_in[2];  // weight_values (NNZ,1) f32
    // d_in[3] = weight_row_lengths (unused by reference)

    const int B = in_sizes[1];
    float* out = (float*)d_out;
    int* offs = (int*)d_ws;  // needs (B+1)*4 bytes

    scan_rows_kernel<<<1, 1024, 0, stream>>>(row_len, offs, B);
    nhot_row_kernel<<<B, ROW_THREADS, 0, stream>>>(ids, wvals, offs, out);
}